// Round 3
// baseline (859.998 us; speedup 1.0000x reference)
//
#include <hip/hip_runtime.h>
#include <math.h>

#define B_ 16
#define C_ 64
#define J_ 100        // 1250-sample blocks per (b,c) row
#define T_ 99
#define KW_ 1250      // half-kernel length (K of the GEMM)
#define KP_ 1280      // K padded to chunk multiple
#define N_ 192        // 32 oc * 3 kh * 2 halves
#define M_ (B_*C_*J_) // 102400
#define BM 128
#define BK 32
#define NCHUNK 40

typedef __attribute__((ext_vector_type(8))) _Float16 half8;
typedef __attribute__((ext_vector_type(4))) float f32x4;
typedef __attribute__((ext_vector_type(2), aligned(8))) float f32x2;  // x rows are 8B-aligned (5000B stride)

// ---------------------------------------------------------------------------
// Kernel 0: one-shot weight conversion fp32 -> fp16, padded [192][1280].
// ---------------------------------------------------------------------------
__global__ __launch_bounds__(256) void wconv_kernel(const float* __restrict__ cw,
                                                    _Float16* __restrict__ wh)
{
    int n = blockIdx.x;               // 0..191
    int o = n / 6, rem = n - o * 6, kh = rem >> 1, hf = rem & 1;
    const float* src = cw + o * 7500 + kh * 2500 + hf * 1250;
    for (int k = threadIdx.x; k < KP_; k += 256)
        wh[n * KP_ + k] = (k < KW_) ? (_Float16)src[k] : (_Float16)0.f;
}

// ---------------------------------------------------------------------------
// Kernel 1: GEMM  P[m'][n] = sum_k x[row(m')][k] * wh[n][k]
//   m' = (b*100 + j)*64 + c ; x row for m' is (b*64+c)*100 + j
// fp16 MFMA 16x16x32, fp32 acc, P stored fp16. WG tile 128x192, 4 waves 2x2.
//
// R2 restructure (after R1's vmcnt fix came back neutral -> not drain-bound):
//   * B is only 480 KB -> fully L2-resident with ~30x reuse across blocks.
//     Read B fragments DIRECTLY from global (16B-aligned L2 hits) instead of
//     LDS-staging them. Deletes 36 KB LDS, all B global_load_lds + ds_reads.
//   * LDS now 16 KB (A dbuf only); A prefetch dist-1 (sufficient: HBM-bound
//     chunk wall >> 900cy load latency), halving areg 32->16 VGPR.
//   * __launch_bounds__(256,3): 3 blocks/CU = 12 waves/CU (was 8), and the
//     800-block grid fits 1.04 dispatch rounds over 768 slots (was 1.56).
//   * One lgkmcnt(0)+barrier per chunk, NO vmcnt at barriers (nothing in
//     VMEM flight needs draining: areg/bfr consumers get compiler waits).
// Race audit: A dbuf; ds_write(ck+2,slot) happens after barrier(ck+1), by
// which every wave's ds_read(ck,slot) is lgkm-complete (the barrier asm
// waits lgkmcnt(0)). bfr reads touch no LDS.
// ---------------------------------------------------------------------------
__global__ __launch_bounds__(256, 3) void gemm_kernel(const float* __restrict__ x,
                                                      const _Float16* __restrict__ wh,
                                                      _Float16* __restrict__ P)
{
    __shared__ __align__(16) _Float16 smA[2][BM * BK];   // 2 x 8 KB

    const int tid  = threadIdx.x;
    const int bm0  = blockIdx.x * BM;
    const int lane = tid & 63;
    const int wave = tid >> 6;
    const int wm   = (wave & 1) * 64;
    const int wn   = (wave >> 1) * 96;
    const int l15  = lane & 15;
    const int lq   = lane >> 4;

    // A staging descriptors: unit u in {0,1}; q=u*256+tid -> row=q>>2, part=q&3
    const float* ap[2]; int koff[2]; int adst[2];
#pragma unroll
    for (int u = 0; u < 2; u++) {
        int q  = u * 256 + tid;
        int rl = q >> 2, p = q & 3;
        int gr = bm0 + rl;                 // m' row
        int b  = gr / 6400;
        int j  = (gr - b * 6400) >> 6;
        int c  = gr & 63;                  // 6400 % 64 == 0
        long xrow = (long)(b * 64 + c) * 100 + j;
        ap[u]   = x + xrow * KW_ + p * 8;  // p*8 included HERE only
        koff[u] = p * 8;
        adst[u] = q * 8;                   // halves
    }
    // B fragment base: row (wn + l15 [+ni*16]), k-offset lq*8 within chunk.
    // Address = wh + (wn+ni*16+l15)*1280 + ck*32 + lq*8  (x2B: 16B aligned).
    const _Float16* bbase = wh + (size_t)(wn + l15) * KP_ + lq * 8;

    f32x4 acc[4][6];
#pragma unroll
    for (int mi = 0; mi < 4; mi++)
#pragma unroll
        for (int ni = 0; ni < 6; ni++) acc[mi][ni] = (f32x4){0.f, 0.f, 0.f, 0.f};

    f32x2 areg[2][4];   // [unit][pair] -- single slot, dist-1 prefetch
#define LOADA(k0)                                                              \
    do {                                                                       \
        _Pragma("unroll") for (int u = 0; u < 2; u++)                          \
        _Pragma("unroll") for (int j2 = 0; j2 < 4; j2++) {                     \
            int k = (k0) + koff[u] + j2 * 2;  /* true element index */         \
            areg[u][j2] = (k + 2 <= KW_)                                       \
                ? *(const f32x2*)(ap[u] + (k0) + j2 * 2)                       \
                : (f32x2){0.f, 0.f};                                           \
        }                                                                      \
    } while (0)

    // Prologue: A(0) in flight.
    LOADA(0);

    for (int ck = 0; ck < NCHUNK; ck++) {
        const int slot = ck & 1;
        _Float16* Ab = &smA[slot][0];

        // B fragment 0 for this chunk: issue EARLY (global, no LDS dep) so
        // L2 latency hides under the convert+barrier.
        half8 bcur = *(const half8*)(bbase + (size_t)ck * BK);

        // convert + write A(ck) from regs (compiler vmcnt-waits areg(ck))
#pragma unroll
        for (int u = 0; u < 2; u++) {
            half8 h;
#pragma unroll
            for (int j2 = 0; j2 < 4; j2++) {
                h[2 * j2]     = (_Float16)areg[u][j2].x;
                h[2 * j2 + 1] = (_Float16)areg[u][j2].y;
            }
            *(half8*)(Ab + adst[u]) = h;
        }

        // publish A writes; no VMEM drain (A(ck+1)/bfr stay in flight).
        asm volatile("s_waitcnt lgkmcnt(0)" ::: "memory");
        __builtin_amdgcn_s_barrier();
        __builtin_amdgcn_sched_barrier(0);   // nothing crosses the barrier

        // dist-1 A prefetch into the (just-consumed) reg slot
        if (ck + 1 < NCHUNK) LOADA((ck + 1) * BK);

        // A fragments from LDS
        half8 afr[4];
#pragma unroll
        for (int mi = 0; mi < 4; mi++)
            afr[mi] = *(const half8*)(Ab + (wm + mi * 16 + l15) * BK + lq * 8);

        // MFMA, B pipelined one fragment ahead (L2 hits)
#pragma unroll
        for (int ni = 0; ni < 6; ni++) {
            half8 bnext = bcur;
            if (ni < 5)
                bnext = *(const half8*)(bbase + (size_t)(ni + 1) * 16 * KP_
                                              + (size_t)ck * BK);
#pragma unroll
            for (int mi = 0; mi < 4; mi++)
                acc[mi][ni] = __builtin_amdgcn_mfma_f32_16x16x32_f16(
                    afr[mi], bcur, acc[mi][ni], 0, 0, 0);
            bcur = bnext;
        }
        // no trailing barrier: next chunk writes the other A buffer
    }

    // epilogue: C/D layout col=lane&15, row=(lane>>4)*4+reg; store fp16
#pragma unroll
    for (int mi = 0; mi < 4; mi++) {
        int mrow = bm0 + wm + mi * 16 + lq * 4;
#pragma unroll
        for (int ni = 0; ni < 6; ni++) {
            int n = wn + ni * 16 + l15;
#pragma unroll
            for (int r2 = 0; r2 < 4; r2++)
                P[(size_t)(mrow + r2) * N_ + n] = (_Float16)acc[mi][ni][r2];
        }
    }
#undef LOADA
}

// ---------------------------------------------------------------------------
// Kernel 2: combine halves + kh taps (replicate-pad clamp), relu, 1x1 conv,
// relu -> z[t][b*64+c]. One WG per (t,b); P blocks are contiguous fp16.
// LDS pad 193 (=1 mod 32): tap reads stride-193 across r=c -> 2-way = free.
// ---------------------------------------------------------------------------
__global__ __launch_bounds__(256) void combine_kernel(const _Float16* __restrict__ P,
                                                      const float* __restrict__ conv_b,
                                                      const float* __restrict__ c2w,
                                                      const float* __restrict__ c2b,
                                                      float* __restrict__ z)
{
    __shared__ float Pl[64][193];
    __shared__ float red[4][64];
    const int t   = blockIdx.x;     // 0..98
    const int b   = blockIdx.y;     // 0..15
    const int tid = threadIdx.x;
    const int c   = tid & 63;
    const int og  = tid >> 6;       // 0..3 -> o in [og*8, og*8+8)

    float v[8];
#pragma unroll
    for (int o = 0; o < 8; o++) v[o] = conv_b[og * 8 + o];

    for (int hf = 0; hf < 2; hf++) {
        const int j = t + hf;       // block index, <= 99
        const _Float16* Pb = P + (size_t)((b * 100 + j) * 64) * N_;  // 64x192 contiguous
        __syncthreads();            // protect Pl from previous phase's readers
#pragma unroll
        for (int i = 0; i < 6; i++) {
            int e   = i * 256 + tid;    // half8 unit index, 0..1535
            half8 h = *(const half8*)(Pb + e * 8);
            int row = e / 24;           // 24 half8 units per 192-wide row
            int col = (e - row * 24) * 8;
#pragma unroll
            for (int u = 0; u < 8; u++) Pl[row][col + u] = (float)h[u];
        }
        __syncthreads();
#pragma unroll
        for (int kh = 0; kh < 3; kh++) {
            int r = c + kh - 1;
            r = r < 0 ? 0 : (r > 63 ? 63 : r);   // replicate padding
#pragma unroll
            for (int o = 0; o < 8; o++)
                v[o] += Pl[r][(og * 8 + o) * 6 + kh * 2 + hf];
        }
    }

    float part = 0.f;
#pragma unroll
    for (int o = 0; o < 8; o++) part += fmaxf(v[o], 0.f) * c2w[og * 8 + o];
    red[og][c] = part;
    __syncthreads();
    if (og == 0) {
        float zz = red[0][c] + red[1][c] + red[2][c] + red[3][c] + c2b[0];
        z[t * (B_ * C_) + b * 64 + c] = fmaxf(zz, 0.f);   // [t][bc] coalesced
    }
}

// ---------------------------------------------------------------------------
// Kernel 3: scalar Elman RNN over T=99 + sigmoid. One thread per (b,c).
// R2: z staged through LDS in two 50-step tiles (<=64KB static) so the
// serial recurrence reads LDS instead of 99 dependent L2/HBM loads.
// ---------------------------------------------------------------------------
__global__ __launch_bounds__(256) void rnn_kernel(const float* __restrict__ z,
                                                  const float* __restrict__ w_ih,
                                                  const float* __restrict__ w_hh,
                                                  const float* __restrict__ b_ih,
                                                  const float* __restrict__ b_hh,
                                                  const float* __restrict__ h0,
                                                  float* __restrict__ out)
{
    __shared__ float zs[50][256];
    const int tid = threadIdx.x;
    const int g   = blockIdx.x * 256 + tid;   // 0..1023 = b*64+c
    const int b   = g >> 6;
    const float wih  = w_ih[0];
    const float whh  = w_hh[0];
    const float bias = b_ih[0] + b_hh[0];
    float h = h0[b];
    for (int t0 = 0; t0 < T_; t0 += 50) {
        const int nt = (T_ - t0) < 50 ? (T_ - t0) : 50;
        __syncthreads();
        for (int tt = 0; tt < nt; tt++)
            zs[tt][tid] = z[(t0 + tt) * (B_ * C_) + g];   // coalesced rows
        __syncthreads();
        for (int tt = 0; tt < nt; tt++)
            h = tanhf(fmaf(wih, zs[tt][tid], fmaf(whh, h, bias)));
    }
    out[g] = 1.f / (1.f + expf(-h));
}

// ---------------------------------------------------------------------------
extern "C" void kernel_launch(void* const* d_in, const int* in_sizes, int n_in,
                              void* d_out, int out_size, void* d_ws, size_t ws_size,
                              hipStream_t stream)
{
    const float* x   = (const float*)d_in[0];
    const float* cw  = (const float*)d_in[1];
    const float* cb  = (const float*)d_in[2];
    const float* c2w = (const float*)d_in[3];
    const float* c2b = (const float*)d_in[4];
    const float* wih = (const float*)d_in[5];
    const float* whh = (const float*)d_in[6];
    const float* bih = (const float*)d_in[7];
    const float* bhh = (const float*)d_in[8];
    const float* h0  = (const float*)d_in[9];
    float* out = (float*)d_out;

    const size_t whbytes = (size_t)N_ * KP_ * sizeof(_Float16);   // 480 KB
    const size_t pbytes  = (size_t)M_ * N_ * sizeof(_Float16);    // 39.3 MB
    const size_t zbytes  = (size_t)B_ * C_ * T_ * sizeof(float);

    if (ws_size < whbytes + pbytes + zbytes) return;  // ws is ~2 GB; never hit

    _Float16* wh = (_Float16*)d_ws;
    _Float16* P  = (_Float16*)((char*)d_ws + whbytes);
    float*    z  = (float*)((char*)d_ws + whbytes + pbytes);

    wconv_kernel<<<N_, 256, 0, stream>>>(cw, wh);
    gemm_kernel<<<M_ / BM, 256, 0, stream>>>(x, wh, P);
    combine_kernel<<<dim3(T_, B_), 256, 0, stream>>>(P, cb, c2w, c2b, z);
    rnn_kernel<<<4, 256, 0, stream>>>(z, wih, whh, bih, bhh, h0, out);
}

// Round 4
// 841.515 us; speedup vs baseline: 1.0220x; 1.0220x over previous
//
#include <hip/hip_runtime.h>
#include <math.h>

#define B_ 16
#define C_ 64
#define T_ 99
#define KW_ 1250      // half-kernel length (K of the GEMM)
#define KP_ 1280      // K padded to chunk multiple
#define N_ 192        // 32 oc * 3 kh * 2 halves
#define M_ (B_*C_*100) // 102400
#define BM 128
#define BK 32
#define NCHUNK 40

typedef __attribute__((ext_vector_type(8))) _Float16 half8;
typedef __attribute__((ext_vector_type(2))) _Float16 half2_t;
typedef __attribute__((ext_vector_type(4))) float f32x4;
typedef __attribute__((ext_vector_type(2), aligned(8))) float f32x2;  // x rows are 8B-aligned (5000B stride)

#define GLD_LDS16(gp, lp) \
    __builtin_amdgcn_global_load_lds((const __attribute__((address_space(1))) void*)(gp), \
                                     (__attribute__((address_space(3))) void*)(lp), 16, 0, 0)

// ---------------------------------------------------------------------------
// Kernel 0: one-shot weight conversion fp32 -> fp16, padded [192][1280].
// ---------------------------------------------------------------------------
__global__ __launch_bounds__(256) void wconv_kernel(const float* __restrict__ cw,
                                                    _Float16* __restrict__ wh)
{
    int n = blockIdx.x;               // 0..191
    int o = n / 6, rem = n - o * 6, kh = rem >> 1, hf = rem & 1;
    const float* src = cw + o * 7500 + kh * 2500 + hf * 1250;
    for (int k = threadIdx.x; k < KP_; k += 256)
        wh[n * KP_ + k] = (k < KW_) ? (_Float16)src[k] : (_Float16)0.f;
}

// ---------------------------------------------------------------------------
// Kernel 0b (R4): pack x (fp32, 5KB rows) -> Apk fp16 in chunk-major-per-tile
// layout Apk[tile][ck][r(128)][k(32)].  Rationale (R3 counters): gemm's
// 128B-granule column-scan of A sustained only 1.04 TB/s (13% HBM) -- DRAM
// page thrash.  This kernel reads x in row-contiguous 5KB spans (page-local)
// and writes Apk in 1KB-contiguous wave stores; gemm then streams Apk in
// 8KB-contiguous chunk blocks.
// Block = 16 consecutive m'-rows (g=blockIdx): tile=g>>3, row-off=(g&7)*16.
// ---------------------------------------------------------------------------
__global__ __launch_bounds__(256) void pack_kernel(const float* __restrict__ x,
                                                   _Float16* __restrict__ Apk)
{
    __shared__ _Float16 As[16][1288];   // 1288: row stride 4 dw mod 32 -> min replay
    const int g   = blockIdx.x;         // 0..6399
    const int tid = threadIdx.x;
    const int i   = tid >> 4;           // row in group, 0..15
    const int s   = tid & 15;
    const int mrow = g * 16 + i;        // m' row
    const int b  = mrow / 6400;
    const int jc = mrow - b * 6400;
    const int j  = jc >> 6;
    const int c  = jc & 63;
    const float* xr = x + ((size_t)(b * 64 + c) * 100 + j) * KW_;

    // phase 1: 16 threads/row, f32x2 sweeps -> 5KB contiguous read per row
#pragma unroll
    for (int sw = 0; sw < 40; sw++) {
        int t = s * 2 + sw * 32;        // 0..1278
        f32x2 v = (t + 2 <= KW_) ? *(const f32x2*)(xr + t) : (f32x2){0.f, 0.f};
        *(half2_t*)(&As[i][t]) = (half2_t){(_Float16)v.x, (_Float16)v.y};
    }
    __syncthreads();

    // phase 2: emit 40 chunk-pieces; per wave one ck => 1KB contiguous store
    const int tile = g >> 3, ro = g & 7;
#pragma unroll
    for (int w = 0; w < 10; w++) {
        int p  = tid + 256 * w;         // 0..2559
        int ck = p >> 6, rem = p & 63, ri = rem >> 2, kq = rem & 3;
        half8 h = *(const half8*)(&As[ri][ck * 32 + kq * 8]);
        *(half8*)(Apk + ((size_t)(tile * NCHUNK + ck) * 128 + ro * 16 + ri) * 32
                      + kq * 8) = h;
    }
}

// ---------------------------------------------------------------------------
// Kernel 1: GEMM  P[m'][n] = sum_k Apk * wh.  fp16 MFMA 16x16x32, fp32 acc.
// WG tile 128x192, 4 waves 2x2.
// R4: A now pre-packed -> per chunk ONE contiguous 8KB global_load_lds block
// (convert + ds_write path deleted).  B also global_load_lds.  All loop VMEM
// = 5 gld_lds/wave/chunk -> counted vmcnt(5), triple-buffered LDS (60KB),
// prefetch dist-2, loads never drained mid-loop (T3+T4).
// Race audit: STAGE(ck+2,b2) issued after barrier(ck); last readers of b2
// were iter ck-1's ds_reads, complete before their wave reached barrier(ck).
// vmcnt count: loop VMEM is exactly 5 gld_lds/iter (ds_reads are lgkmcnt;
// P stores are post-loop) -> at iter ck wait, outstanding = {ck:5, ck+1:5},
// vmcnt(5) completes ck; final iter drains with vmcnt(0).
// ---------------------------------------------------------------------------
__global__ __launch_bounds__(256, 2) void gemm_kernel(const _Float16* __restrict__ Apk,
                                                      const _Float16* __restrict__ wh,
                                                      _Float16* __restrict__ P)
{
    __shared__ __align__(16) _Float16 smA[3][BM * BK];   // 3 x 8 KB
    __shared__ __align__(16) _Float16 smB[3][N_ * BK];   // 3 x 12 KB (60 KB tot)

    const int tid  = threadIdx.x;
    const int bt   = blockIdx.x;
    const int lane = tid & 63;
    const int wave = tid >> 6;
    const int wq   = wave * 64;          // wave-uniform staging unit base
    const int wm   = (wave & 1) * 64;
    const int wn   = (wave >> 1) * 96;
    const int l15  = lane & 15;
    const int lq   = lane >> 4;

    // B staging srcs: unit q = wq + 256*s + lane; n=q>>2, kq=q&3
    const _Float16* bp[3];
#pragma unroll
    for (int s = 0; s < 3; s++) {
        int q = wq + 256 * s + lane;
        bp[s] = wh + (size_t)(q >> 2) * KP_ + (q & 3) * 8;
    }
    const _Float16* abase = Apk + ((size_t)(bt * NCHUNK) << 12);

    // gld_lds dst must be wave-uniform (HW appends lane*16B); src is per-lane.
#define STAGE(ck_, buf_) do {                                                    \
        const _Float16* As_ = abase + ((size_t)(ck_) << 12);                     \
        GLD_LDS16(As_ + (wq) * 8 + lane * 8,       &smA[buf_][(wq) * 8]);        \
        GLD_LDS16(As_ + (wq + 256) * 8 + lane * 8, &smA[buf_][(wq + 256) * 8]);  \
        GLD_LDS16(bp[0] + (size_t)(ck_) * BK,      &smB[buf_][(wq) * 8]);        \
        GLD_LDS16(bp[1] + (size_t)(ck_) * BK,      &smB[buf_][(wq + 256) * 8]);  \
        GLD_LDS16(bp[2] + (size_t)(ck_) * BK,      &smB[buf_][(wq + 512) * 8]);  \
    } while (0)

    f32x4 acc[4][6];
#pragma unroll
    for (int mi = 0; mi < 4; mi++)
#pragma unroll
        for (int ni = 0; ni < 6; ni++) acc[mi][ni] = (f32x4){0.f, 0.f, 0.f, 0.f};

    STAGE(0, 0);
    STAGE(1, 1);

    int bi = 0;
    for (int ck = 0; ck < NCHUNK; ck++) {
        if (ck + 1 < NCHUNK) {
            asm volatile("s_waitcnt vmcnt(5)" ::: "memory");   // chunk ck landed
        } else {
            asm volatile("s_waitcnt vmcnt(0)" ::: "memory");   // final drain
        }
        __builtin_amdgcn_s_barrier();
        __builtin_amdgcn_sched_barrier(0);

        if (ck + 2 < NCHUNK) {
            int b2 = bi + 2; if (b2 >= 3) b2 -= 3;
            STAGE(ck + 2, b2);
        }

        const _Float16* Ab = &smA[bi][0];
        const _Float16* Bb = &smB[bi][0];
        half8 afr[4], bfr[6];
#pragma unroll
        for (int mi = 0; mi < 4; mi++)
            afr[mi] = *(const half8*)(Ab + (wm + mi * 16 + l15) * BK + lq * 8);
#pragma unroll
        for (int ni = 0; ni < 6; ni++)
            bfr[ni] = *(const half8*)(Bb + (wn + ni * 16 + l15) * BK + lq * 8);
#pragma unroll
        for (int mi = 0; mi < 4; mi++)
#pragma unroll
            for (int ni = 0; ni < 6; ni++)
                acc[mi][ni] = __builtin_amdgcn_mfma_f32_16x16x32_f16(
                    afr[mi], bfr[ni], acc[mi][ni], 0, 0, 0);

        bi = (bi == 2) ? 0 : bi + 1;
        // no trailing barrier: next iter's STAGE writes a different buffer
    }
#undef STAGE

    // epilogue: C/D layout col=lane&15, row=(lane>>4)*4+reg; store fp16
    const int bm0 = bt * BM;
#pragma unroll
    for (int mi = 0; mi < 4; mi++) {
        int mrow = bm0 + wm + mi * 16 + lq * 4;
#pragma unroll
        for (int ni = 0; ni < 6; ni++) {
            int n = wn + ni * 16 + l15;
#pragma unroll
            for (int r2 = 0; r2 < 4; r2++)
                P[(size_t)(mrow + r2) * N_ + n] = (_Float16)acc[mi][ni][r2];
        }
    }
}

// ---------------------------------------------------------------------------
// Kernel 2: combine halves + kh taps (replicate-pad clamp), relu, 1x1 conv,
// relu -> z[t][b*64+c]. One WG per (t,b); P blocks are contiguous fp16.
// LDS pad 193 (=1 mod 32): tap reads stride-193 across r=c -> 2-way = free.
// ---------------------------------------------------------------------------
__global__ __launch_bounds__(256) void combine_kernel(const _Float16* __restrict__ P,
                                                      const float* __restrict__ conv_b,
                                                      const float* __restrict__ c2w,
                                                      const float* __restrict__ c2b,
                                                      float* __restrict__ z)
{
    __shared__ float Pl[64][193];
    __shared__ float red[4][64];
    const int t   = blockIdx.x;     // 0..98
    const int b   = blockIdx.y;     // 0..15
    const int tid = threadIdx.x;
    const int c   = tid & 63;
    const int og  = tid >> 6;       // 0..3 -> o in [og*8, og*8+8)

    float v[8];
#pragma unroll
    for (int o = 0; o < 8; o++) v[o] = conv_b[og * 8 + o];

    for (int hf = 0; hf < 2; hf++) {
        const int j = t + hf;       // block index, <= 99
        const _Float16* Pb = P + (size_t)((b * 100 + j) * 64) * N_;  // 64x192 contiguous
        __syncthreads();            // protect Pl from previous phase's readers
#pragma unroll
        for (int i = 0; i < 6; i++) {
            int e   = i * 256 + tid;    // half8 unit index, 0..1535
            half8 h = *(const half8*)(Pb + e * 8);
            int row = e / 24;           // 24 half8 units per 192-wide row
            int col = (e - row * 24) * 8;
#pragma unroll
            for (int u = 0; u < 8; u++) Pl[row][col + u] = (float)h[u];
        }
        __syncthreads();
#pragma unroll
        for (int kh = 0; kh < 3; kh++) {
            int r = c + kh - 1;
            r = r < 0 ? 0 : (r > 63 ? 63 : r);   // replicate padding
#pragma unroll
            for (int o = 0; o < 8; o++)
                v[o] += Pl[r][(og * 8 + o) * 6 + kh * 2 + hf];
        }
    }

    float part = 0.f;
#pragma unroll
    for (int o = 0; o < 8; o++) part += fmaxf(v[o], 0.f) * c2w[og * 8 + o];
    red[og][c] = part;
    __syncthreads();
    if (og == 0) {
        float zz = red[0][c] + red[1][c] + red[2][c] + red[3][c] + c2b[0];
        z[t * (B_ * C_) + b * 64 + c] = fmaxf(zz, 0.f);   // [t][bc] coalesced
    }
}

// ---------------------------------------------------------------------------
// Kernel 3: scalar Elman RNN over T=99 + sigmoid. One thread per (b,c).
// z staged through LDS in 50-step tiles so the serial recurrence reads LDS.
// ---------------------------------------------------------------------------
__global__ __launch_bounds__(256) void rnn_kernel(const float* __restrict__ z,
                                                  const float* __restrict__ w_ih,
                                                  const float* __restrict__ w_hh,
                                                  const float* __restrict__ b_ih,
                                                  const float* __restrict__ b_hh,
                                                  const float* __restrict__ h0,
                                                  float* __restrict__ out)
{
    __shared__ float zs[50][256];
    const int tid = threadIdx.x;
    const int g   = blockIdx.x * 256 + tid;   // 0..1023 = b*64+c
    const int b   = g >> 6;
    const float wih  = w_ih[0];
    const float whh  = w_hh[0];
    const float bias = b_ih[0] + b_hh[0];
    float h = h0[b];
    for (int t0 = 0; t0 < T_; t0 += 50) {
        const int nt = (T_ - t0) < 50 ? (T_ - t0) : 50;
        __syncthreads();
        for (int tt = 0; tt < nt; tt++)
            zs[tt][tid] = z[(t0 + tt) * (B_ * C_) + g];   // coalesced rows
        __syncthreads();
        for (int tt = 0; tt < nt; tt++)
            h = tanhf(fmaf(wih, zs[tt][tid], fmaf(whh, h, bias)));
    }
    out[g] = 1.f / (1.f + expf(-h));
}

// ---------------------------------------------------------------------------
extern "C" void kernel_launch(void* const* d_in, const int* in_sizes, int n_in,
                              void* d_out, int out_size, void* d_ws, size_t ws_size,
                              hipStream_t stream)
{
    const float* x   = (const float*)d_in[0];
    const float* cw  = (const float*)d_in[1];
    const float* cb  = (const float*)d_in[2];
    const float* c2w = (const float*)d_in[3];
    const float* c2b = (const float*)d_in[4];
    const float* wih = (const float*)d_in[5];
    const float* whh = (const float*)d_in[6];
    const float* bih = (const float*)d_in[7];
    const float* bhh = (const float*)d_in[8];
    const float* h0  = (const float*)d_in[9];
    float* out = (float*)d_out;

    const size_t whbytes  = (size_t)N_ * KP_ * sizeof(_Float16);            // 480 KB
    const size_t apkbytes = (size_t)(M_ / BM) * NCHUNK * 4096 * sizeof(_Float16); // 262 MB
    const size_t pbytes   = (size_t)M_ * N_ * sizeof(_Float16);             // 39.3 MB
    const size_t zbytes   = (size_t)B_ * C_ * T_ * sizeof(float);

    if (ws_size < whbytes + apkbytes + pbytes + zbytes) return;  // ws ~2GB; never hit

    _Float16* wh  = (_Float16*)d_ws;
    _Float16* Apk = (_Float16*)((char*)d_ws + whbytes);
    _Float16* P   = (_Float16*)((char*)d_ws + whbytes + apkbytes);
    float*    z   = (float*)((char*)d_ws + whbytes + apkbytes + pbytes);

    wconv_kernel<<<N_, 256, 0, stream>>>(cw, wh);
    pack_kernel<<<M_ / 16, 256, 0, stream>>>(x, Apk);
    gemm_kernel<<<M_ / BM, 256, 0, stream>>>(Apk, wh, P);
    combine_kernel<<<dim3(T_, B_), 256, 0, stream>>>(P, cb, c2w, c2b, z);
    rnn_kernel<<<4, 256, 0, stream>>>(z, wih, whh, bih, bhh, h0, out);
}

// Round 8
// 785.428 us; speedup vs baseline: 1.0949x; 1.0714x over previous
//
#include <hip/hip_runtime.h>
#include <math.h>

#define B_ 16
#define C_ 64
#define T_ 99
#define KW_ 1250      // half-kernel length (K of the GEMM)
#define KP_ 1280      // K padded to chunk multiple
#define N_ 192        // 32 oc * 3 kh * 2 halves
#define M_ (B_*C_*100) // 102400
#define BM 128
#define BK 32
#define NSC 10        // super-chunks of 128 k
#define ASTRIDE 136   // LDS A row stride in halves (272B: 16B-aligned, 68dw%32=4 -> b128 balanced)

typedef __attribute__((ext_vector_type(8))) _Float16 half8;
typedef __attribute__((ext_vector_type(2))) _Float16 half2_t;
typedef __attribute__((ext_vector_type(4))) float f32x4;
typedef __attribute__((ext_vector_type(2), aligned(8))) float f32x2;  // x rows are 8B-aligned (5000B stride)

// ---------------------------------------------------------------------------
// Kernel 0: one-shot weight conversion fp32 -> fp16, padded [192][1280].
// ---------------------------------------------------------------------------
__global__ __launch_bounds__(256) void wconv_kernel(const float* __restrict__ cw,
                                                    _Float16* __restrict__ wh)
{
    int n = blockIdx.x;               // 0..191
    int o = n / 6, rem = n - o * 6, kh = rem >> 1, hf = rem & 1;
    const float* src = cw + o * 7500 + kh * 2500 + hf * 1250;
    for (int k = threadIdx.x; k < KP_; k += 256)
        wh[n * KP_ + k] = (k < KW_) ? (_Float16)src[k] : (_Float16)0.f;
}

// ---------------------------------------------------------------------------
// Kernel 1 (R5): FUSED pack+GEMM.  P[m'][n] = sum_k x[row(m')][k] * wh[n][k].
// R4 decomposition: fixed harness overhead ~517us; pack+gemm ~299us with
// 524 MB avoidable Apk round-trip.  This kernel deletes Apk: per super-chunk
// (128 k), each block reads its 128 A-rows as 512B-CONTIGUOUS spans (f32x2
// half-wave segments -> 256B coalesced; x rows only 8B-aligned), converts
// fp32->fp16 in-register, stages into a 35KB LDS tile, then runs 4 MFMA
// chunks from LDS.  B fragments direct from L2 (480KB wh; 384MB aggregate).
//   - LDS row stride 136 halves: 272B (16B-aligned for b128; 68dw%32=4 ->
//     frag reads bank-balanced; b32 writes conflict-free).
//   - 2 raw barriers per super-chunk (lgkmcnt only -- A-prefetch loads stay
//     in flight across barriers; no vmcnt drain).
//   - dist-1 register prefetch of next A super-chunk (64 VGPR).
// Race audit: CONVWRITE(sc) sits between barrier#2(sc-1) (all frag reads of
// sc-1 done) and barrier#1(sc) (publishes writes).  B loads touch no LDS.
// Tail: KW=1250 even -> f32x2 at k<=1248 always fully valid; k>=1250 zeros
// (wh is zero-padded past 1250, so products match).
// ---------------------------------------------------------------------------
__global__ __launch_bounds__(256, 2) void gemm_kernel(const float* __restrict__ x,
                                                      const _Float16* __restrict__ wh,
                                                      _Float16* __restrict__ P)
{
    __shared__ __align__(16) _Float16 smA[BM * ASTRIDE];   // 34.8 KB

    const int tid  = threadIdx.x;
    const int bt   = blockIdx.x;          // 0..799
    const int bm0  = bt * BM;
    const int lane = tid & 63;
    const int wave = tid >> 6;
    const int wm   = (wave & 1) * 64;
    const int wn   = (wave >> 1) * 96;
    const int l15  = lane & 15;
    const int lq   = lane >> 4;

    // A staging geometry: half-wave h=tid>>5 owns rows h*16..h*16+15.
    const int h   = tid >> 5;             // 0..7
    const int lw  = tid & 31;
    const int lw2 = lw * 2;
    const int rbase = h * 16;
    // m-row gr = bm0 + r;  b = bt/50;  j = (bt%50)*2 + (r>>6);  c = r&63.
    // For r = h*16+i (i<16): r>>6 = h>>2, c = (h&3)*16 + i  (no wrap).
    // xrow(i) = (b*64 + (h&3)*16 + i)*100 + (bt%50)*2 + (h>>2); stride in i
    // is +100 rows = +125000 floats (constant).
    const int bb   = bt / 50;
    const int tloc = bt - bb * 50;
    const long xrow0 = (long)(bb * 64 + (h & 3) * 16) * 100 + tloc * 2 + (h >> 2);
    const float* apx = x + xrow0 * KW_ + lw2;   // i-stride 125000 floats

    // B fragment base: wh + (wn+ni*16+l15)*KP + ck*32 + lq*8 (16B aligned).
    const _Float16* bbase = wh + (size_t)(wn + l15) * KP_ + lq * 8;

    f32x4 acc[4][6];
#pragma unroll
    for (int mi = 0; mi < 4; mi++)
#pragma unroll
        for (int ni = 0; ni < 6; ni++) acc[mi][ni] = (f32x4){0.f, 0.f, 0.f, 0.f};

    f32x2 areg[16][2];   // next super-chunk A: 16 rows x 2 spans x 2 floats

#define LOADA(sc_) do {                                                          \
        const float* p_ = apx + (sc_) * 128;                                     \
        if ((sc_) < NSC - 1) {                                                   \
            _Pragma("unroll") for (int i = 0; i < 16; i++)                       \
            _Pragma("unroll") for (int w = 0; w < 2; w++)                        \
                areg[i][w] = *(const f32x2*)(p_ + (size_t)i * 125000 + w * 64);  \
        } else {                                                                 \
            _Pragma("unroll") for (int i = 0; i < 16; i++)                       \
            _Pragma("unroll") for (int w = 0; w < 2; w++) {                      \
                int k_ = (NSC - 1) * 128 + w * 64 + lw2;                         \
                areg[i][w] = (k_ <= KW_ - 2)                                     \
                    ? *(const f32x2*)(p_ + (size_t)i * 125000 + w * 64)          \
                    : (f32x2){0.f, 0.f};                                         \
            }                                                                    \
        }                                                                        \
    } while (0)

    LOADA(0);

    for (int sc = 0; sc < NSC; sc++) {
        // convert + write A(sc) from areg (compiler vmcnt-waits areg loads)
#pragma unroll
        for (int i = 0; i < 16; i++) {
            const int r = rbase + i;
#pragma unroll
            for (int w = 0; w < 2; w++) {
                half2_t hh = {(_Float16)areg[i][w].x, (_Float16)areg[i][w].y};
                *(half2_t*)(smA + r * ASTRIDE + w * 64 + lw2) = hh;
            }
        }

        // B frags for first chunk of this sc: no LDS dep, issue pre-barrier
        half8 bfr[6];
#pragma unroll
        for (int ni = 0; ni < 6; ni++)
            bfr[ni] = *(const half8*)(bbase + (size_t)ni * 16 * KP_
                                            + (size_t)(sc * 4) * BK);

        asm volatile("s_waitcnt lgkmcnt(0)" ::: "memory");
        __builtin_amdgcn_s_barrier();
        __builtin_amdgcn_sched_barrier(0);   // A(sc) published; no vmcnt drain

        if (sc + 1 < NSC) LOADA(sc + 1);     // dist-1 A prefetch (regs free)

#pragma unroll
        for (int ckl = 0; ckl < 4; ckl++) {
            if (ckl > 0) {
#pragma unroll
                for (int ni = 0; ni < 6; ni++)
                    bfr[ni] = *(const half8*)(bbase + (size_t)ni * 16 * KP_
                                                    + (size_t)(sc * 4 + ckl) * BK);
            }
            half8 afr[4];
#pragma unroll
            for (int mi = 0; mi < 4; mi++)
                afr[mi] = *(const half8*)(smA + (wm + mi * 16 + l15) * ASTRIDE
                                              + ckl * 32 + lq * 8);
#pragma unroll
            for (int mi = 0; mi < 4; mi++)
#pragma unroll
                for (int ni = 0; ni < 6; ni++)
                    acc[mi][ni] = __builtin_amdgcn_mfma_f32_16x16x32_f16(
                        afr[mi], bfr[ni], acc[mi][ni], 0, 0, 0);
        }

        asm volatile("s_waitcnt lgkmcnt(0)" ::: "memory");
        __builtin_amdgcn_s_barrier();        // all frag reads done before next write
        __builtin_amdgcn_sched_barrier(0);
    }
#undef LOADA

    // epilogue: C/D layout col=lane&15, row=(lane>>4)*4+reg; store fp16
#pragma unroll
    for (int mi = 0; mi < 4; mi++) {
        int mrow = bm0 + wm + mi * 16 + lq * 4;
#pragma unroll
        for (int ni = 0; ni < 6; ni++) {
            int n = wn + ni * 16 + l15;
#pragma unroll
            for (int r2 = 0; r2 < 4; r2++)
                P[(size_t)(mrow + r2) * N_ + n] = (_Float16)acc[mi][ni][r2];
        }
    }
}

// ---------------------------------------------------------------------------
// Kernel 2: combine halves + kh taps (replicate-pad clamp), relu, 1x1 conv,
// relu -> z[t][b*64+c]. One WG per (t,b); P blocks are contiguous fp16.
// LDS pad 193 (=1 mod 32): tap reads stride-193 across r=c -> 2-way = free.
// ---------------------------------------------------------------------------
__global__ __launch_bounds__(256) void combine_kernel(const _Float16* __restrict__ P,
                                                      const float* __restrict__ conv_b,
                                                      const float* __restrict__ c2w,
                                                      const float* __restrict__ c2b,
                                                      float* __restrict__ z)
{
    __shared__ float Pl[64][193];
    __shared__ float red[4][64];
    const int t   = blockIdx.x;     // 0..98
    const int b   = blockIdx.y;     // 0..15
    const int tid = threadIdx.x;
    const int c   = tid & 63;
    const int og  = tid >> 6;       // 0..3 -> o in [og*8, og*8+8)

    float v[8];
#pragma unroll
    for (int o = 0; o < 8; o++) v[o] = conv_b[og * 8 + o];

    for (int hf = 0; hf < 2; hf++) {
        const int j = t + hf;       // block index, <= 99
        const _Float16* Pb = P + (size_t)((b * 100 + j) * 64) * N_;  // 64x192 contiguous
        __syncthreads();            // protect Pl from previous phase's readers
#pragma unroll
        for (int i = 0; i < 6; i++) {
            int e   = i * 256 + tid;    // half8 unit index, 0..1535
            half8 hdat = *(const half8*)(Pb + e * 8);
            int row = e / 24;           // 24 half8 units per 192-wide row
            int col = (e - row * 24) * 8;
#pragma unroll
            for (int u = 0; u < 8; u++) Pl[row][col + u] = (float)hdat[u];
        }
        __syncthreads();
#pragma unroll
        for (int kh = 0; kh < 3; kh++) {
            int r = c + kh - 1;
            r = r < 0 ? 0 : (r > 63 ? 63 : r);   // replicate padding
#pragma unroll
            for (int o = 0; o < 8; o++)
                v[o] += Pl[r][(og * 8 + o) * 6 + kh * 2 + hf];
        }
    }

    float part = 0.f;
#pragma unroll
    for (int o = 0; o < 8; o++) part += fmaxf(v[o], 0.f) * c2w[og * 8 + o];
    red[og][c] = part;
    __syncthreads();
    if (og == 0) {
        float zz = red[0][c] + red[1][c] + red[2][c] + red[3][c] + c2b[0];
        z[t * (B_ * C_) + b * 64 + c] = fmaxf(zz, 0.f);   // [t][bc] coalesced
    }
}

// ---------------------------------------------------------------------------
// Kernel 3: scalar Elman RNN over T=99 + sigmoid. One thread per (b,c).
// z staged through LDS in 50-step tiles so the serial recurrence reads LDS.
// ---------------------------------------------------------------------------
__global__ __launch_bounds__(256) void rnn_kernel(const float* __restrict__ z,
                                                  const float* __restrict__ w_ih,
                                                  const float* __restrict__ w_hh,
                                                  const float* __restrict__ b_ih,
                                                  const float* __restrict__ b_hh,
                                                  const float* __restrict__ h0,
                                                  float* __restrict__ out)
{
    __shared__ float zs[50][256];
    const int tid = threadIdx.x;
    const int g   = blockIdx.x * 256 + tid;   // 0..1023 = b*64+c
    const int b   = g >> 6;
    const float wih  = w_ih[0];
    const float whh  = w_hh[0];
    const float bias = b_ih[0] + b_hh[0];
    float h = h0[b];
    for (int t0 = 0; t0 < T_; t0 += 50) {
        const int nt = (T_ - t0) < 50 ? (T_ - t0) : 50;
        __syncthreads();
        for (int tt = 0; tt < nt; tt++)
            zs[tt][tid] = z[(t0 + tt) * (B_ * C_) + g];   // coalesced rows
        __syncthreads();
        for (int tt = 0; tt < nt; tt++)
            h = tanhf(fmaf(wih, zs[tt][tid], fmaf(whh, h, bias)));
    }
    out[g] = 1.f / (1.f + expf(-h));
}

// ---------------------------------------------------------------------------
extern "C" void kernel_launch(void* const* d_in, const int* in_sizes, int n_in,
                              void* d_out, int out_size, void* d_ws, size_t ws_size,
                              hipStream_t stream)
{
    const float* x   = (const float*)d_in[0];
    const float* cw  = (const float*)d_in[1];
    const float* cb  = (const float*)d_in[2];
    const float* c2w = (const float*)d_in[3];
    const float* c2b = (const float*)d_in[4];
    const float* wih = (const float*)d_in[5];
    const float* whh = (const float*)d_in[6];
    const float* bih = (const float*)d_in[7];
    const float* bhh = (const float*)d_in[8];
    const float* h0  = (const float*)d_in[9];
    float* out = (float*)d_out;

    const size_t whbytes = (size_t)N_ * KP_ * sizeof(_Float16);   // 480 KB
    const size_t pbytes  = (size_t)M_ * N_ * sizeof(_Float16);    // 39.3 MB
    const size_t zbytes  = (size_t)B_ * C_ * T_ * sizeof(float);

    if (ws_size < whbytes + pbytes + zbytes) return;  // ws ~2GB; never hit

    _Float16* wh = (_Float16*)d_ws;
    _Float16* P  = (_Float16*)((char*)d_ws + whbytes);
    float*    z  = (float*)((char*)d_ws + whbytes + pbytes);

    wconv_kernel<<<N_, 256, 0, stream>>>(cw, wh);
    gemm_kernel<<<M_ / BM, 256, 0, stream>>>(x, wh, P);
    combine_kernel<<<dim3(T_, B_), 256, 0, stream>>>(P, cb, c2w, c2b, z);
    rnn_kernel<<<4, 256, 0, stream>>>(z, wih, whh, bih, bhh, h0, out);
}